// Round 11
// baseline (311.547 us; speedup 1.0000x reference)
//
#include <hip/hip_runtime.h>
#include <hip/hip_bf16.h>
#include <cstdint>

#define CAP 32
typedef __hip_bfloat16 bf16;
typedef __attribute__((ext_vector_type(8))) short short8;
typedef __attribute__((ext_vector_type(4))) float f32x4;

__device__ __forceinline__ float sb2f(short s) {
  unsigned int u = ((unsigned int)(unsigned short)s) << 16;
  return __uint_as_float(u);
}
__device__ __forceinline__ short f2sb(float f) {
  bf16 h = __float2bfloat16(f);
  return *reinterpret_cast<short*>(&h);
}

// Head-padded column layout for H1/HL2: col' = 80*h + j, j in [0,78), h in [0,10).
// Cols with j in {78,79} and col' in [800,832) are zero pads. This makes every
// 8-col thread slice in k_agg1 belong to exactly ONE head (1 weight read/row).

__device__ __forceinline__ void edge_sd(const int* __restrict__ ei, int e, int f,
                                        int& src, int& dst) {
  if (e < 100000) {
    if (f) { src = ei[2 * e]; dst = ei[200000 + 2 * e]; }
    else   { src = ei[e];     dst = ei[100000 + e]; }
  } else { src = dst = e - 100000; }
  src = min(max(src, 0), 49999);
  dst = min(max(dst, 0), 49999);
}

// ---------- prep: zero cnt/g + bf16 padded/transposed copies + Wa ----------
// xb path vectorized: one short8 store per thread (8 cols).
__global__ void k_prep(const float* __restrict__ x, const float* __restrict__ W1,
                       const float* __restrict__ W2, const float* __restrict__ aw1,
                       const float* __restrict__ dw1, bf16* __restrict__ xb,
                       bf16* __restrict__ W1t, bf16* __restrict__ W2t,
                       bf16* __restrict__ Wat, float* __restrict__ zp, int zeroWords) {
  int i = blockIdx.x * 256 + threadIdx.x;
  if (i < zeroWords) zp[i] = 0.f;
  const int n_xbv = 50000 * 12;   // short8 groups of xb
  const int n_w1 = 832 * 96;
  const int n_w2 = 128 * 832;
  const int n_wa = 32 * 96;
  if (i < n_xbv) {
    int r = i / 12, kg = i - r * 12;
    const float* xr = x + (size_t)r * 78;
    const int k0 = kg * 8;
    short8 ov;
#pragma unroll
    for (int c = 0; c < 8; c++) {
      int k = k0 + c;
      ov[c] = f2sb(k < 78 ? xr[k] : 0.f);
    }
    *(short8*)((short*)xb + (size_t)r * 96 + k0) = ov;
  } else if (i < n_xbv + n_w1) {
    // W1t row n' = head-padded output column: n' = 80h + j -> source col 78h + j
    int jdx = i - n_xbv;
    int np = jdx / 96, k = jdx - np * 96;
    int h = np / 80, j = np - h * 80;
    float v = 0.f;
    if (k < 78 && np < 800 && j < 78) v = W1[k * 780 + (h * 78 + j)];
    W1t[jdx] = __float2bfloat16(v);
  } else if (i < n_xbv + n_w1 + n_w2) {
    // W2t[c][k'] with head-padded K: k' = 80h + j -> source row 78h + j
    int jdx = i - n_xbv - n_w1;
    int c = jdx / 832, kp = jdx - c * 832;
    int h = kp / 80, j = kp - h * 80;
    float v = 0.f;
    if (kp < 800 && j < 78) v = W2[(h * 78 + j) * 128 + c];
    W2t[jdx] = __float2bfloat16(v);
  } else if (i < n_xbv + n_w1 + n_w2 + n_wa) {
    int jdx = i - n_xbv - n_w1 - n_w2;
    int c = jdx / 96, k = jdx - c * 96;
    float s = 0.f;
    if (k < 78 && c < 20) {
      const float* w = (c < 10) ? aw1 : dw1;
      int h = (c < 10) ? c : c - 10;
      const float* wrow = W1 + k * 780 + h * 78;
      const float* arow = w + h * 78;
      for (int q = 0; q < 78; q++) s += wrow[q] * arow[q];
    }
    Wat[c * 96 + k] = __float2bfloat16(s);
  }
}

// ---------- GEMM1 (MFMA bf16): h1[50000,832] = xb @ W1t^T + b1 (bias folded in) ----------
// LDS lifetime-managed: A-fragments cached in registers after staging (Als dead),
// alpha1 computed up front (Wls dead), then the chunk loop reuses the same LDS
// region for Bls (shorts) and Cls (floats). 54 KB -> 23.3 KB => ~7 blocks/CU.
__global__ __launch_bounds__(256) void k_gemm1(const bf16* __restrict__ xb,
                                               const bf16* __restrict__ W1t,
                                               const bf16* __restrict__ Wat,
                                               const float* __restrict__ b1,
                                               bf16* __restrict__ H1,
                                               float* __restrict__ as1,
                                               float* __restrict__ ad1) {
  // phase 1: [0,13312) = Als (64x104 shorts), [13312,19968) = Wls (32x104 shorts)
  // phase 2: [0,17408) = Bls (64x104 shorts) / Cls (64x68 floats), barrier-separated
  __shared__ __align__(16) char smem[19968];
  __shared__ float b1s[832];
  short* Als = (short*)smem;
  short* Wls = (short*)(smem + 13312);
  short* Bls = (short*)smem;
  float* Cls = (float*)smem;
  const int t = threadIdx.x;
  const int w = t >> 6, l = t & 63, l15 = l & 15, q = l >> 4;
  const int rowBase = blockIdx.x * 64;
  // stage A once (64x96), Wa once (32x96), b1 once (head-padded order)
  for (int s = t; s < 768; s += 256) {
    int row = s / 12, kg = s - row * 12;
    short8 v = {};
    int gr = rowBase + row;
    if (gr < 50000) v = *(const short8*)((const short*)xb + (size_t)gr * 96 + kg * 8);
    *(short8*)&Als[row * 104 + kg * 8] = v;
  }
  for (int s = t; s < 384; s += 256) {
    int row = s / 12, kg = s - row * 12;
    *(short8*)&Wls[row * 104 + kg * 8] =
        *(const short8*)((const short*)Wat + (size_t)row * 96 + kg * 8);
  }
  for (int s = t; s < 832; s += 256) {
    int h = s / 80, j = s - h * 80;
    b1s[s] = (s < 800 && j < 78) ? b1[h * 78 + j] : 0.f;
  }
  __syncthreads();
  // cache A fragments in registers (same 3 LDS slots every chunk)
  short8 afrag[3];
#pragma unroll
  for (int ks = 0; ks < 3; ks++)
    afrag[ks] = *(const short8*)&Als[(w * 16 + l15) * 104 + ks * 32 + q * 8];
  // fused alpha1 up front: [64x96] @ Wa^T (afrag + Wls; no atomics)
  {
    f32x4 acc2[2] = {};
#pragma unroll
    for (int ks = 0; ks < 3; ks++) {
#pragma unroll
      for (int nt = 0; nt < 2; nt++) {
        short8 b = *(const short8*)&Wls[(nt * 16 + l15) * 104 + ks * 32 + q * 8];
        acc2[nt] = __builtin_amdgcn_mfma_f32_16x16x32_bf16(afrag[ks], b, acc2[nt], 0, 0, 0);
      }
    }
    const int gr0 = rowBase + w * 16 + q * 4;
#pragma unroll
    for (int nt = 0; nt < 2; nt++) {
      int c = nt * 16 + l15;
#pragma unroll
      for (int r = 0; r < 4; r++) {
        int gr = gr0 + r;
        if (gr < 50000) {
          if (c < 10)       as1[gr * 10 + c] = acc2[nt][r];
          else if (c < 20)  ad1[gr * 10 + (c - 10)] = acc2[nt][r];
        }
      }
    }
  }
  // prefetch B chunk 0 into registers (3 short8/thread)
  short8 breg[3];
  int bn[3], bk[3];
#pragma unroll
  for (int i = 0; i < 3; i++) {
    int s = t + i * 256;
    bn[i] = s / 12; bk[i] = s - bn[i] * 12;
    breg[i] = *(const short8*)((const short*)W1t + (size_t)bn[i] * 96 + bk[i] * 8);
  }
  for (int cc = 0; cc < 13; cc++) {
    __syncthreads();  // prev Cls consumed (and cc==0: afrag/Wls reads done)
#pragma unroll
    for (int i = 0; i < 3; i++) *(short8*)&Bls[bn[i] * 104 + bk[i] * 8] = breg[i];
    if (cc < 12) {
#pragma unroll
      for (int i = 0; i < 3; i++)
        breg[i] = *(const short8*)((const short*)W1t +
                                   (size_t)((cc + 1) * 64 + bn[i]) * 96 + bk[i] * 8);
    }
    __syncthreads();
    f32x4 acc[4] = {};
#pragma unroll
    for (int ks = 0; ks < 3; ks++) {
#pragma unroll
      for (int nt = 0; nt < 4; nt++) {
        short8 b = *(const short8*)&Bls[(nt * 16 + l15) * 104 + ks * 32 + q * 8];
        acc[nt] = __builtin_amdgcn_mfma_f32_16x16x32_bf16(afrag[ks], b, acc[nt], 0, 0, 0);
      }
    }
    // C transpose via LDS (Cls aliases Bls; all Bls reads done) -> 16-B stores
    __syncthreads();
#pragma unroll
    for (int nt = 0; nt < 4; nt++)
#pragma unroll
      for (int r = 0; r < 4; r++)
        Cls[(w * 16 + q * 4 + r) * 68 + nt * 16 + l15] = acc[nt][r];
    __syncthreads();
    {
      int r = t >> 2, c0 = (t & 3) * 16;
      int gr = rowBase + r;
      if (gr < 50000) {
        short8 o0, o1;
#pragma unroll
        for (int c = 0; c < 8; c++) o0[c] = f2sb(Cls[r * 68 + c0 + c] + b1s[cc * 64 + c0 + c]);
#pragma unroll
        for (int c = 0; c < 8; c++) o1[c] = f2sb(Cls[r * 68 + c0 + 8 + c] + b1s[cc * 64 + c0 + 8 + c]);
        short* dst = (short*)H1 + (size_t)gr * 832 + cc * 64 + c0;
        *(short8*)dst = o0;
        *(short8*)(dst + 8) = o1;
      }
    }
  }
}

// ---------- CSR bucket scatter (src only); per-block int64 detect; publishes flag ----------
__global__ void k_scatter(const int* __restrict__ ei, int* __restrict__ cnt,
                          int* __restrict__ csr, int* __restrict__ flag) {
  __shared__ int sf;
  const int t = threadIdx.x;
  if (t == 0) sf = 0;
  __syncthreads();
  int v = 0;
  for (int i = 1 + 2 * t; i < 2000; i += 512) v |= ei[i];
  if (v) atomicOr(&sf, 1);
  __syncthreads();
  const int f = (sf == 0) ? 1 : 0;  // 1 => int64 layout
  if (blockIdx.x == 0 && t == 0) flag[0] = f;  // for k_agg2 (stream-ordered)
  int e = blockIdx.x * 256 + t;
  if (e >= 150000) return;
  int src, dst;
  edge_sd(ei, e, f, src, dst);
  int pos = atomicAdd(&cnt[dst], 1);
  if (pos < CAP) csr[dst * CAP + pos] = src;
}

// ---------- aggregate layer1: head-padded layout; 1 weight read per row ----------
// 2 nodes per 256-thread block. Direct global gather; each thread's 8 cols are
// within one head (head = tt/10), so one ds_read weight per gathered row.
__global__ __launch_bounds__(256) void k_agg1(const bf16* __restrict__ H1,
                                              const float* __restrict__ as1,
                                              const float* __restrict__ ad1,
                                              const int* __restrict__ csr,
                                              const int* __restrict__ cnt,
                                              bf16* __restrict__ HL2) {
  __shared__ float sexw[2][CAP * 10];
  __shared__ float sden[2][16];
  __shared__ int ssrc[2][CAP];
  __shared__ int scnt[2];
  const int t = threadIdx.x;
  const int sub = t >> 7, tt = t & 127;
  const int n = blockIdx.x * 2 + sub;
  if (t < 2) scnt[t] = min(cnt[blockIdx.x * 2 + t], CAP);
  if (t >= 32 && t < 64) { int z = t - 32; sden[z >> 4][z & 15] = 0.f; }
  __syncthreads();
  const int cn = scnt[sub];
  if (tt < cn) ssrc[sub][tt] = csr[n * CAP + tt];
  __syncthreads();
  for (int wv = tt; wv < cn * 10; wv += 128) {
    int k = wv / 10, h = wv - k * 10;
    int src = ssrc[sub][k];
    float e = as1[src * 10 + h] + ad1[n * 10 + h];
    e = e >= 0.f ? e : 0.2f * e;
    float ex = __expf(e);
    sexw[sub][wv] = ex;  // unnormalized; denominator applied in epilogue
    atomicAdd(&sden[sub][h], ex);
  }
  __syncthreads();
  if (tt < 100) {
    const int head = tt / 10;
    const int j0 = tt * 8;
    float acc[8] = {};
    const float* sw = sexw[sub] + head;
    const short* H1s = (const short*)H1;
    for (int k = 0; k < cn; k++) {
      int src = ssrc[sub][k];
      short8 hv = *(const short8*)(H1s + (size_t)src * 832 + j0);
      float wk = sw[k * 10];
#pragma unroll
      for (int c = 0; c < 8; c++) acc[c] += wk * sb2f(hv[c]);
    }
    const float r0 = 1.f / (sden[sub][head] + 1e-16f);
    short8 ov;
#pragma unroll
    for (int c = 0; c < 8; c++) {
      float v = acc[c] * r0;
      v = v > 0.f ? v : __expf(v) - 1.f;  // within-head pad cols: elu(0)=0
      ov[c] = f2sb(v);
    }
    *(short8*)((short*)HL2 + (size_t)n * 832 + j0) = ov;
  } else if (tt < 104) {
    short8 z = {};
    *(short8*)((short*)HL2 + (size_t)n * 832 + tt * 8) = z;  // cols 800..831 = 0
  }
}

// ---------- GEMM2 (MFMA bf16, zero-staging): h2 = hl2 @ W2t^T, fused alpha2 ----------
// No LDS staging, no K-loop barriers: A fragments read directly from global
// (16 rows x 64 B segments/wave, full cache-line use; 4 waves share the A-subtile
// via L1/L2), B fragments read from the L2-resident W2t (213 KB, shared by all
// blocks). Only the cross-wave alpha reduce uses LDS (2 KB) + one barrier.
__global__ __launch_bounds__(256) void k_gemm2(const bf16* __restrict__ A,
                                               const bf16* __restrict__ W2t,
                                               const float* __restrict__ AW2,
                                               const float* __restrict__ DW2,
                                               bf16* __restrict__ H2,
                                               float* __restrict__ as2,
                                               float* __restrict__ ad2) {
  __shared__ float sS[4][64], sD[4][64];
  const int t = threadIdx.x;
  const int w = t >> 6, l = t & 63, l15 = l & 15, q = l >> 4;
  const int rowBase = blockIdx.x * 64;
  const short* Ab = (const short*)A;
  const short* Wb = (const short*)W2t;
  size_t arow[4];
#pragma unroll
  for (int mt = 0; mt < 4; mt++) {
    int gr = min(rowBase + mt * 16 + l15, 49999);  // clamped; OOB rows never stored
    arow[mt] = (size_t)gr * 832;
  }
  size_t brow[2];
#pragma unroll
  for (int ntl = 0; ntl < 2; ntl++) {
    int col = (w * 2 + ntl) * 16 + l15;
    brow[ntl] = (size_t)col * 832;
  }
  f32x4 acc[4][2] = {};
  for (int kb = 0; kb < 832; kb += 64) {
    const int ko = kb + q * 8;
#pragma unroll
    for (int ks = 0; ks < 2; ks++) {
      short8 b0 = *(const short8*)(Wb + brow[0] + ko + ks * 32);
      short8 b1 = *(const short8*)(Wb + brow[1] + ko + ks * 32);
#pragma unroll
      for (int mt = 0; mt < 4; mt++) {
        short8 a = *(const short8*)(Ab + arow[mt] + ko + ks * 32);
        acc[mt][0] = __builtin_amdgcn_mfma_f32_16x16x32_bf16(a, b0, acc[mt][0], 0, 0, 0);
        acc[mt][1] = __builtin_amdgcn_mfma_f32_16x16x32_bf16(a, b1, acc[mt][1], 0, 0, 0);
      }
    }
  }
  const int col0 = w * 32 + l15, col1 = col0 + 16;
  const float aw0 = AW2[col0], aw1 = AW2[col1];
  const float dw0 = DW2[col0], dw1 = DW2[col1];
  f32x4 sp[4], dp[4];
#pragma unroll
  for (int mt = 0; mt < 4; mt++) {
    sp[mt] = acc[mt][0] * aw0 + acc[mt][1] * aw1;
    dp[mt] = acc[mt][0] * dw0 + acc[mt][1] * dw1;
  }
#pragma unroll
  for (int m = 1; m < 16; m <<= 1) {
#pragma unroll
    for (int mt = 0; mt < 4; mt++)
#pragma unroll
      for (int r = 0; r < 4; r++) {
        sp[mt][r] += __shfl_xor(sp[mt][r], m, 64);
        dp[mt][r] += __shfl_xor(dp[mt][r], m, 64);
      }
  }
  if (l15 == 0) {
#pragma unroll
    for (int mt = 0; mt < 4; mt++)
#pragma unroll
      for (int r = 0; r < 4; r++) {
        sS[w][mt * 16 + q * 4 + r] = sp[mt][r];
        sD[w][mt * 16 + q * 4 + r] = dp[mt][r];
      }
  }
#pragma unroll
  for (int mt = 0; mt < 4; mt++) {
    int gr0 = rowBase + mt * 16 + q * 4;
#pragma unroll
    for (int ntl = 0; ntl < 2; ntl++) {
      int gc = w * 32 + ntl * 16 + l15;
#pragma unroll
      for (int r = 0; r < 4; r++) {
        int gr = gr0 + r;
        if (gr < 50000) H2[(size_t)gr * 128 + gc] = __float2bfloat16(acc[mt][ntl][r]);
      }
    }
  }
  __syncthreads();
  if (t < 64) {
    int gr = rowBase + t;
    if (gr < 50000) as2[gr] = sS[0][t] + sS[1][t] + sS[2][t] + sS[3][t];
  } else if (t < 128) {
    int r2 = t - 64;
    int gr = rowBase + r2;
    if (gr < 50000) ad2[gr] = sD[0][r2] + sD[1][r2] + sD[2][r2] + sD[3][r2];
  }
}

// ---------- aggregate layer2: ONE WAVE PER NODE (no barriers, no LDS) ----------
// 4 nodes per 256-thread block. Lane k holds edge k's (src, exp); denominator via
// wave shfl reduce; k-loop broadcasts (src,w) via uniform-index shfl (readlane);
// each lane accumulates 2 columns from one ushort2 load (256 B/row coalesced).
__global__ __launch_bounds__(256) void k_agg2(const bf16* __restrict__ H2,
                                              const float* __restrict__ as2,
                                              const float* __restrict__ ad2,
                                              const int* __restrict__ csr,
                                              const int* __restrict__ cnt,
                                              const float* __restrict__ b2,
                                              const int* __restrict__ batch,
                                              const int* __restrict__ flag,
                                              float* __restrict__ g) {
  const int t = threadIdx.x;
  const int wid = t >> 6, lane = t & 63;
  const int n = blockIdx.x * 4 + wid;
  const int f = flag[0];
  int b = f ? batch[2 * n] : batch[n];
  b = min(max(b, 0), 1249);
  const int cn = min(cnt[n], CAP);
  int srcv = 0;
  float exv = 0.f;
  if (lane < cn) {
    srcv = csr[n * CAP + lane];
    float e = as2[srcv] + ad2[n];
    e = e >= 0.f ? e : 0.2f * e;
    exv = __expf(e);
  }
  float den = exv;
#pragma unroll
  for (int m = 1; m < 64; m <<= 1) den += __shfl_xor(den, m, 64);
  const float winv = 1.f / (den + 1e-16f);
  const short* H2s = (const short*)H2;
  float a0 = 0.f, a1 = 0.f;
  // 2-deep pipelined gather; uniform shfl index -> readlane broadcast
  unsigned int hv = 0;
  float wcur = 0.f;
  {
    int s0 = __shfl(srcv, 0, 64);
    wcur = __shfl(exv, 0, 64);
    hv = *(const unsigned int*)(H2s + (size_t)s0 * 128 + lane * 2);
  }
  for (int k = 1; k <= cn; k++) {
    unsigned int hn = 0;
    float wn = 0.f;
    if (k < cn) {
      int sk = __shfl(srcv, k, 64);
      wn = __shfl(exv, k, 64);
      hn = *(const unsigned int*)(H2s + (size_t)sk * 128 + lane * 2);
    }
    a0 += wcur * sb2f((short)(hv & 0xffff));
    a1 += wcur * sb2f((short)(hv >> 16));
    hv = hn;
    wcur = wn;
  }
  const int c0 = lane * 2;
  float v0 = a0 * winv + b2[c0];
  float v1 = a1 * winv + b2[c0 + 1];
  v0 = v0 > 0.f ? v0 : 0.f;
  v1 = v1 > 0.f ? v1 : 0.f;
  atomicMax((int*)&g[b * 128 + c0], __float_as_int(v0));      // v >= 0
  atomicMax((int*)&g[b * 128 + c0 + 1], __float_as_int(v1));
}

// ---------- final FC + ReLU -> f32 out ----------
__global__ __launch_bounds__(128) void k_fc(const float* __restrict__ g,
                                            const float* __restrict__ fw,
                                            const float* __restrict__ fb,
                                            float* __restrict__ out) {
  const int n = blockIdx.x, t = threadIdx.x;
  __shared__ float grow[128];
  grow[t] = g[n * 128 + t];
  __syncthreads();
  float acc = fb[t];
  for (int k = 0; k < 128; k++) acc += grow[k] * fw[k * 128 + t];
  out[n * 128 + t] = acc > 0.f ? acc : 0.f;
}

extern "C" void kernel_launch(void* const* d_in, const int* in_sizes, int n_in,
                              void* d_out, int out_size, void* d_ws, size_t ws_size,
                              hipStream_t stream) {
  const float* x     = (const float*)d_in[0];
  const int*   ei    = (const int*)d_in[1];
  const int*   batch = (const int*)d_in[2];
  const float* W1    = (const float*)d_in[3];
  const float* as1w  = (const float*)d_in[4];
  const float* ad1w  = (const float*)d_in[5];
  const float* b1    = (const float*)d_in[6];
  const float* W2    = (const float*)d_in[7];
  const float* as2w  = (const float*)d_in[8];
  const float* ad2w  = (const float*)d_in[9];
  const float* b2    = (const float*)d_in[10];
  const float* fcw   = (const float*)d_in[11];
  const float* fcb   = (const float*)d_in[12];
  float* out = (float*)d_out;

  char* p = (char*)d_ws;
  size_t off = 0;
  auto alloc = [&](size_t bytes) -> void* {
    void* r = p + off;
    off = (off + bytes + 15) & ~(size_t)15;
    return r;
  };
  // ---- zero region (cnt + g) ----
  int*   cnt = (int*)  alloc(50000 * 4);
  float* g   = (float*)alloc(160000 * 4);
  size_t zeroWords = off / 4;
  // ---- rest (~191 MB) ----
  float* as1 = (float*)alloc(500000 * 4);
  float* ad1 = (float*)alloc(500000 * 4);
  float* as2 = (float*)alloc(50000 * 4);
  float* ad2 = (float*)alloc(50000 * 4);
  bf16*  W1t = (bf16*) alloc((size_t)832 * 96 * 2);
  bf16*  W2t = (bf16*) alloc((size_t)128 * 832 * 2);
  bf16*  Wat = (bf16*) alloc((size_t)32 * 96 * 2);
  bf16*  h1  = (bf16*) alloc((size_t)50000 * 832 * 2);
  bf16*  hl2 = (bf16*) alloc((size_t)50000 * 832 * 2);
  int*   csr = (int*)  alloc((size_t)50000 * CAP * 4);
  // union: xb (9.6 MB, dead after gemm1) aliases h2 (12.8 MB, born in gemm2)
  void*  uni = alloc((size_t)50000 * 128 * 2);
  bf16*  xb  = (bf16*)uni;
  bf16*  h2  = (bf16*)uni;
  int*   flag = (int*) alloc(16);
  (void)ws_size; (void)in_sizes; (void)n_in; (void)out_size;

  int prepN = 50000 * 12 + 832 * 96 + 128 * 832 + 32 * 96;
  k_prep<<<(prepN + 255) / 256, 256, 0, stream>>>(
      x, W1, W2, as1w, ad1w, xb, W1t, W2t, Wat, (float*)d_ws, (int)zeroWords);

  k_gemm1<<<782, 256, 0, stream>>>(xb, W1t, Wat, b1, h1, as1, ad1);
  k_scatter<<<(150000 + 255) / 256, 256, 0, stream>>>(ei, cnt, csr, flag);
  k_agg1<<<25000, 256, 0, stream>>>(h1, as1, ad1, csr, cnt, hl2);
  k_gemm2<<<782, 256, 0, stream>>>(hl2, W2t, as2w, ad2w, h2, as2, ad2);
  k_agg2<<<12500, 256, 0, stream>>>(h2, as2, ad2, csr, cnt, b2, batch, flag, g);
  k_fc<<<1250, 128, 0, stream>>>(g, fcw, fcb, out);
}

// Round 12
// 269.551 us; speedup vs baseline: 1.1558x; 1.1558x over previous
//
#include <hip/hip_runtime.h>
#include <hip/hip_bf16.h>
#include <cstdint>

#define CAP 32
typedef __hip_bfloat16 bf16;
typedef __attribute__((ext_vector_type(8))) short short8;
typedef __attribute__((ext_vector_type(4))) float f32x4;

__device__ __forceinline__ float sb2f(short s) {
  unsigned int u = ((unsigned int)(unsigned short)s) << 16;
  return __uint_as_float(u);
}
__device__ __forceinline__ short f2sb(float f) {
  bf16 h = __float2bfloat16(f);
  return *reinterpret_cast<short*>(&h);
}

// Head-padded column layout for H1/HL2: col' = 80*h + j, j in [0,78), h in [0,10).
// Cols with j in {78,79} and col' in [800,832) are zero pads. This makes every
// 8-col thread slice in k_agg1 belong to exactly ONE head (1 weight read/row).

__device__ __forceinline__ void edge_sd(const int* __restrict__ ei, int e, int f,
                                        int& src, int& dst) {
  if (e < 100000) {
    if (f) { src = ei[2 * e]; dst = ei[200000 + 2 * e]; }
    else   { src = ei[e];     dst = ei[100000 + e]; }
  } else { src = dst = e - 100000; }
  src = min(max(src, 0), 49999);
  dst = min(max(dst, 0), 49999);
}

// ---------- prep: zero cnt/g + bf16 padded/transposed copies + Wa ----------
// xb path vectorized: one short8 store per thread (8 cols).
__global__ void k_prep(const float* __restrict__ x, const float* __restrict__ W1,
                       const float* __restrict__ W2, const float* __restrict__ aw1,
                       const float* __restrict__ dw1, bf16* __restrict__ xb,
                       bf16* __restrict__ W1t, bf16* __restrict__ W2t,
                       bf16* __restrict__ Wat, float* __restrict__ zp, int zeroWords) {
  int i = blockIdx.x * 256 + threadIdx.x;
  if (i < zeroWords) zp[i] = 0.f;
  const int n_xbv = 50000 * 12;   // short8 groups of xb
  const int n_w1 = 832 * 96;
  const int n_w2 = 128 * 832;
  const int n_wa = 32 * 96;
  if (i < n_xbv) {
    int r = i / 12, kg = i - r * 12;
    const float* xr = x + (size_t)r * 78;
    const int k0 = kg * 8;
    short8 ov;
#pragma unroll
    for (int c = 0; c < 8; c++) {
      int k = k0 + c;
      ov[c] = f2sb(k < 78 ? xr[k] : 0.f);
    }
    *(short8*)((short*)xb + (size_t)r * 96 + k0) = ov;
  } else if (i < n_xbv + n_w1) {
    // W1t row n' = head-padded output column: n' = 80h + j -> source col 78h + j
    int jdx = i - n_xbv;
    int np = jdx / 96, k = jdx - np * 96;
    int h = np / 80, j = np - h * 80;
    float v = 0.f;
    if (k < 78 && np < 800 && j < 78) v = W1[k * 780 + (h * 78 + j)];
    W1t[jdx] = __float2bfloat16(v);
  } else if (i < n_xbv + n_w1 + n_w2) {
    // W2t[c][k'] with head-padded K: k' = 80h + j -> source row 78h + j
    int jdx = i - n_xbv - n_w1;
    int c = jdx / 832, kp = jdx - c * 832;
    int h = kp / 80, j = kp - h * 80;
    float v = 0.f;
    if (kp < 800 && j < 78) v = W2[(h * 78 + j) * 128 + c];
    W2t[jdx] = __float2bfloat16(v);
  } else if (i < n_xbv + n_w1 + n_w2 + n_wa) {
    int jdx = i - n_xbv - n_w1 - n_w2;
    int c = jdx / 96, k = jdx - c * 96;
    float s = 0.f;
    if (k < 78 && c < 20) {
      const float* w = (c < 10) ? aw1 : dw1;
      int h = (c < 10) ? c : c - 10;
      const float* wrow = W1 + k * 780 + h * 78;
      const float* arow = w + h * 78;
      for (int q = 0; q < 78; q++) s += wrow[q] * arow[q];
    }
    Wat[c * 96 + k] = __float2bfloat16(s);
  }
}

// ---------- GEMM1 (MFMA bf16): h1[50000,832] = xb @ W1t^T + b1 (bias folded in) ----------
// LDS lifetime-managed: A-fragments cached in registers after staging (Als dead),
// alpha1 computed up front (Wls dead), then the chunk loop reuses the same LDS
// region for Bls (shorts) and Cls (floats). 54 KB -> 23.3 KB => ~7 blocks/CU.
__global__ __launch_bounds__(256) void k_gemm1(const bf16* __restrict__ xb,
                                               const bf16* __restrict__ W1t,
                                               const bf16* __restrict__ Wat,
                                               const float* __restrict__ b1,
                                               bf16* __restrict__ H1,
                                               float* __restrict__ as1,
                                               float* __restrict__ ad1) {
  // phase 1: [0,13312) = Als (64x104 shorts), [13312,19968) = Wls (32x104 shorts)
  // phase 2: [0,17408) = Bls (64x104 shorts) / Cls (64x68 floats), barrier-separated
  __shared__ __align__(16) char smem[19968];
  __shared__ float b1s[832];
  short* Als = (short*)smem;
  short* Wls = (short*)(smem + 13312);
  short* Bls = (short*)smem;
  float* Cls = (float*)smem;
  const int t = threadIdx.x;
  const int w = t >> 6, l = t & 63, l15 = l & 15, q = l >> 4;
  const int rowBase = blockIdx.x * 64;
  // stage A once (64x96), Wa once (32x96), b1 once (head-padded order)
  for (int s = t; s < 768; s += 256) {
    int row = s / 12, kg = s - row * 12;
    short8 v = {};
    int gr = rowBase + row;
    if (gr < 50000) v = *(const short8*)((const short*)xb + (size_t)gr * 96 + kg * 8);
    *(short8*)&Als[row * 104 + kg * 8] = v;
  }
  for (int s = t; s < 384; s += 256) {
    int row = s / 12, kg = s - row * 12;
    *(short8*)&Wls[row * 104 + kg * 8] =
        *(const short8*)((const short*)Wat + (size_t)row * 96 + kg * 8);
  }
  for (int s = t; s < 832; s += 256) {
    int h = s / 80, j = s - h * 80;
    b1s[s] = (s < 800 && j < 78) ? b1[h * 78 + j] : 0.f;
  }
  __syncthreads();
  // cache A fragments in registers (same 3 LDS slots every chunk)
  short8 afrag[3];
#pragma unroll
  for (int ks = 0; ks < 3; ks++)
    afrag[ks] = *(const short8*)&Als[(w * 16 + l15) * 104 + ks * 32 + q * 8];
  // fused alpha1 up front: [64x96] @ Wa^T (afrag + Wls; no atomics)
  {
    f32x4 acc2[2] = {};
#pragma unroll
    for (int ks = 0; ks < 3; ks++) {
#pragma unroll
      for (int nt = 0; nt < 2; nt++) {
        short8 b = *(const short8*)&Wls[(nt * 16 + l15) * 104 + ks * 32 + q * 8];
        acc2[nt] = __builtin_amdgcn_mfma_f32_16x16x32_bf16(afrag[ks], b, acc2[nt], 0, 0, 0);
      }
    }
    const int gr0 = rowBase + w * 16 + q * 4;
#pragma unroll
    for (int nt = 0; nt < 2; nt++) {
      int c = nt * 16 + l15;
#pragma unroll
      for (int r = 0; r < 4; r++) {
        int gr = gr0 + r;
        if (gr < 50000) {
          if (c < 10)       as1[gr * 10 + c] = acc2[nt][r];
          else if (c < 20)  ad1[gr * 10 + (c - 10)] = acc2[nt][r];
        }
      }
    }
  }
  // prefetch B chunk 0 into registers (3 short8/thread)
  short8 breg[3];
  int bn[3], bk[3];
#pragma unroll
  for (int i = 0; i < 3; i++) {
    int s = t + i * 256;
    bn[i] = s / 12; bk[i] = s - bn[i] * 12;
    breg[i] = *(const short8*)((const short*)W1t + (size_t)bn[i] * 96 + bk[i] * 8);
  }
  for (int cc = 0; cc < 13; cc++) {
    __syncthreads();  // prev Cls consumed (and cc==0: afrag/Wls reads done)
#pragma unroll
    for (int i = 0; i < 3; i++) *(short8*)&Bls[bn[i] * 104 + bk[i] * 8] = breg[i];
    if (cc < 12) {
#pragma unroll
      for (int i = 0; i < 3; i++)
        breg[i] = *(const short8*)((const short*)W1t +
                                   (size_t)((cc + 1) * 64 + bn[i]) * 96 + bk[i] * 8);
    }
    __syncthreads();
    f32x4 acc[4] = {};
#pragma unroll
    for (int ks = 0; ks < 3; ks++) {
#pragma unroll
      for (int nt = 0; nt < 4; nt++) {
        short8 b = *(const short8*)&Bls[(nt * 16 + l15) * 104 + ks * 32 + q * 8];
        acc[nt] = __builtin_amdgcn_mfma_f32_16x16x32_bf16(afrag[ks], b, acc[nt], 0, 0, 0);
      }
    }
    // C transpose via LDS (Cls aliases Bls; all Bls reads done) -> 16-B stores
    __syncthreads();
#pragma unroll
    for (int nt = 0; nt < 4; nt++)
#pragma unroll
      for (int r = 0; r < 4; r++)
        Cls[(w * 16 + q * 4 + r) * 68 + nt * 16 + l15] = acc[nt][r];
    __syncthreads();
    {
      int r = t >> 2, c0 = (t & 3) * 16;
      int gr = rowBase + r;
      if (gr < 50000) {
        short8 o0, o1;
#pragma unroll
        for (int c = 0; c < 8; c++) o0[c] = f2sb(Cls[r * 68 + c0 + c] + b1s[cc * 64 + c0 + c]);
#pragma unroll
        for (int c = 0; c < 8; c++) o1[c] = f2sb(Cls[r * 68 + c0 + 8 + c] + b1s[cc * 64 + c0 + 8 + c]);
        short* dst = (short*)H1 + (size_t)gr * 832 + cc * 64 + c0;
        *(short8*)dst = o0;
        *(short8*)(dst + 8) = o1;
      }
    }
  }
}

// ---------- CSR bucket scatter (src only); per-block int64 detect; publishes flag ----------
__global__ void k_scatter(const int* __restrict__ ei, int* __restrict__ cnt,
                          int* __restrict__ csr, int* __restrict__ flag) {
  __shared__ int sf;
  const int t = threadIdx.x;
  if (t == 0) sf = 0;
  __syncthreads();
  int v = 0;
  for (int i = 1 + 2 * t; i < 2000; i += 512) v |= ei[i];
  if (v) atomicOr(&sf, 1);
  __syncthreads();
  const int f = (sf == 0) ? 1 : 0;  // 1 => int64 layout
  if (blockIdx.x == 0 && t == 0) flag[0] = f;  // for k_agg2 (stream-ordered)
  int e = blockIdx.x * 256 + t;
  if (e >= 150000) return;
  int src, dst;
  edge_sd(ei, e, f, src, dst);
  int pos = atomicAdd(&cnt[dst], 1);
  if (pos < CAP) csr[dst * CAP + pos] = src;
}

// ---------- aggregate layer1: head-padded layout; 1 weight read per row ----------
// 2 nodes per 256-thread block. Direct global gather; each thread's 8 cols are
// within one head (head = tt/10), so one ds_read weight per gathered row.
__global__ __launch_bounds__(256) void k_agg1(const bf16* __restrict__ H1,
                                              const float* __restrict__ as1,
                                              const float* __restrict__ ad1,
                                              const int* __restrict__ csr,
                                              const int* __restrict__ cnt,
                                              bf16* __restrict__ HL2) {
  __shared__ float sexw[2][CAP * 10];
  __shared__ float sden[2][16];
  __shared__ int ssrc[2][CAP];
  __shared__ int scnt[2];
  const int t = threadIdx.x;
  const int sub = t >> 7, tt = t & 127;
  const int n = blockIdx.x * 2 + sub;
  if (t < 2) scnt[t] = min(cnt[blockIdx.x * 2 + t], CAP);
  if (t >= 32 && t < 64) { int z = t - 32; sden[z >> 4][z & 15] = 0.f; }
  __syncthreads();
  const int cn = scnt[sub];
  if (tt < cn) ssrc[sub][tt] = csr[n * CAP + tt];
  __syncthreads();
  for (int wv = tt; wv < cn * 10; wv += 128) {
    int k = wv / 10, h = wv - k * 10;
    int src = ssrc[sub][k];
    float e = as1[src * 10 + h] + ad1[n * 10 + h];
    e = e >= 0.f ? e : 0.2f * e;
    float ex = __expf(e);
    sexw[sub][wv] = ex;  // unnormalized; denominator applied in epilogue
    atomicAdd(&sden[sub][h], ex);
  }
  __syncthreads();
  if (tt < 100) {
    const int head = tt / 10;
    const int j0 = tt * 8;
    float acc[8] = {};
    const float* sw = sexw[sub] + head;
    const short* H1s = (const short*)H1;
    for (int k = 0; k < cn; k++) {
      int src = ssrc[sub][k];
      short8 hv = *(const short8*)(H1s + (size_t)src * 832 + j0);
      float wk = sw[k * 10];
#pragma unroll
      for (int c = 0; c < 8; c++) acc[c] += wk * sb2f(hv[c]);
    }
    const float r0 = 1.f / (sden[sub][head] + 1e-16f);
    short8 ov;
#pragma unroll
    for (int c = 0; c < 8; c++) {
      float v = acc[c] * r0;
      v = v > 0.f ? v : __expf(v) - 1.f;  // within-head pad cols: elu(0)=0
      ov[c] = f2sb(v);
    }
    *(short8*)((short*)HL2 + (size_t)n * 832 + j0) = ov;
  } else if (tt < 104) {
    short8 z = {};
    *(short8*)((short*)HL2 + (size_t)n * 832 + tt * 8) = z;  // cols 800..831 = 0
  }
}

// ---------- GEMM2 (MFMA bf16, reg-prefetch pipeline): h2 = hl2 @ W2t^T, fused alpha2 ----------
// K dimension is in head-padded order (W2t rows permuted/zero-padded to match).
__global__ __launch_bounds__(256) void k_gemm2(const bf16* __restrict__ A,
                                               const bf16* __restrict__ W2t,
                                               const float* __restrict__ AW2,
                                               const float* __restrict__ DW2,
                                               bf16* __restrict__ H2,
                                               float* __restrict__ as2,
                                               float* __restrict__ ad2) {
  __shared__ __align__(16) short Als[64 * 72];
  __shared__ __align__(16) short Bls[128 * 72];
  __shared__ float sAW[128], sDW[128];
  __shared__ float sS[4][64], sD[4][64];
  const int t = threadIdx.x;
  const int w = t >> 6, l = t & 63, l15 = l & 15, q = l >> 4;
  const int rowBase = blockIdx.x * 64;
  if (t < 128) sAW[t] = AW2[t];
  else         sDW[t - 128] = DW2[t - 128];
  const int ar = t >> 2, ak = t & 3;
  short8 areg[2], breg[4];
  {
    int gr0 = rowBase + ar;
#pragma unroll
    for (int i = 0; i < 2; i++) {
      short8 v = {};
      int gr = gr0;
      if (gr < 50000)
        v = *(const short8*)((const short*)A + (size_t)gr * 832 + 0 + (ak * 2 + i) * 8);
      areg[i] = v;
    }
#pragma unroll
    for (int i = 0; i < 4; i++) {
      int s = t + i * 256;
      int col = s >> 3, kg = s & 7;
      breg[i] = *(const short8*)((const short*)W2t + (size_t)col * 832 + 0 + kg * 8);
    }
  }
  f32x4 acc[4][2] = {};
  for (int kb = 0; kb < 832; kb += 64) {
    __syncthreads();
#pragma unroll
    for (int i = 0; i < 2; i++)
      *(short8*)&Als[ar * 72 + (ak * 2 + i) * 8] = areg[i];
#pragma unroll
    for (int i = 0; i < 4; i++) {
      int s = t + i * 256;
      int col = s >> 3, kg = s & 7;
      *(short8*)&Bls[col * 72 + kg * 8] = breg[i];
    }
    if (kb < 768) {
      int kn = kb + 64;
      int gr = rowBase + ar;
#pragma unroll
      for (int i = 0; i < 2; i++) {
        short8 v = {};
        if (gr < 50000)
          v = *(const short8*)((const short*)A + (size_t)gr * 832 + kn + (ak * 2 + i) * 8);
        areg[i] = v;
      }
#pragma unroll
      for (int i = 0; i < 4; i++) {
        int s = t + i * 256;
        int col = s >> 3, kg = s & 7;
        breg[i] = *(const short8*)((const short*)W2t + (size_t)col * 832 + kn + kg * 8);
      }
    }
    __syncthreads();
#pragma unroll
    for (int ks = 0; ks < 2; ks++) {
      short8 a[4];
#pragma unroll
      for (int mt = 0; mt < 4; mt++)
        a[mt] = *(const short8*)&Als[(mt * 16 + l15) * 72 + ks * 32 + q * 8];
#pragma unroll
      for (int ntl = 0; ntl < 2; ntl++) {
        short8 b = *(const short8*)&Bls[((w * 2 + ntl) * 16 + l15) * 72 + ks * 32 + q * 8];
#pragma unroll
        for (int mt = 0; mt < 4; mt++)
          acc[mt][ntl] = __builtin_amdgcn_mfma_f32_16x16x32_bf16(a[mt], b, acc[mt][ntl], 0, 0, 0);
      }
    }
  }
  const int col0 = w * 32 + l15, col1 = col0 + 16;
  const float aw0 = sAW[col0], aw1 = sAW[col1];
  const float dw0 = sDW[col0], dw1 = sDW[col1];
  f32x4 sp[4], dp[4];
#pragma unroll
  for (int mt = 0; mt < 4; mt++) {
    sp[mt] = acc[mt][0] * aw0 + acc[mt][1] * aw1;
    dp[mt] = acc[mt][0] * dw0 + acc[mt][1] * dw1;
  }
#pragma unroll
  for (int m = 1; m < 16; m <<= 1) {
#pragma unroll
    for (int mt = 0; mt < 4; mt++)
#pragma unroll
      for (int r = 0; r < 4; r++) {
        sp[mt][r] += __shfl_xor(sp[mt][r], m, 64);
        dp[mt][r] += __shfl_xor(dp[mt][r], m, 64);
      }
  }
  if (l15 == 0) {
#pragma unroll
    for (int mt = 0; mt < 4; mt++)
#pragma unroll
      for (int r = 0; r < 4; r++) {
        sS[w][mt * 16 + q * 4 + r] = sp[mt][r];
        sD[w][mt * 16 + q * 4 + r] = dp[mt][r];
      }
  }
#pragma unroll
  for (int mt = 0; mt < 4; mt++) {
    int gr0 = rowBase + mt * 16 + q * 4;
#pragma unroll
    for (int ntl = 0; ntl < 2; ntl++) {
      int gc = w * 32 + ntl * 16 + l15;
#pragma unroll
      for (int r = 0; r < 4; r++) {
        int gr = gr0 + r;
        if (gr < 50000) H2[(size_t)gr * 128 + gc] = __float2bfloat16(acc[mt][ntl][r]);
      }
    }
  }
  __syncthreads();
  if (t < 64) {
    int gr = rowBase + t;
    if (gr < 50000) as2[gr] = sS[0][t] + sS[1][t] + sS[2][t] + sS[3][t];
  } else if (t < 128) {
    int r2 = t - 64;
    int gr = rowBase + r2;
    if (gr < 50000) ad2[gr] = sD[0][r2] + sD[1][r2] + sD[2][r2] + sD[3][r2];
  }
}

// ---------- aggregate layer2: ONE WAVE PER NODE (no barriers, no LDS) ----------
// 4 nodes per 256-thread block. Lane k holds edge k's (src, exp); denominator via
// wave shfl reduce; k-loop broadcasts (src,w) via uniform-index shfl (readlane);
// each lane accumulates 2 columns from one ushort2 load (256 B/row coalesced).
__global__ __launch_bounds__(256) void k_agg2(const bf16* __restrict__ H2,
                                              const float* __restrict__ as2,
                                              const float* __restrict__ ad2,
                                              const int* __restrict__ csr,
                                              const int* __restrict__ cnt,
                                              const float* __restrict__ b2,
                                              const int* __restrict__ batch,
                                              const int* __restrict__ flag,
                                              float* __restrict__ g) {
  const int t = threadIdx.x;
  const int wid = t >> 6, lane = t & 63;
  const int n = blockIdx.x * 4 + wid;
  const int f = flag[0];
  int b = f ? batch[2 * n] : batch[n];
  b = min(max(b, 0), 1249);
  const int cn = min(cnt[n], CAP);
  int srcv = 0;
  float exv = 0.f;
  if (lane < cn) {
    srcv = csr[n * CAP + lane];
    float e = as2[srcv] + ad2[n];
    e = e >= 0.f ? e : 0.2f * e;
    exv = __expf(e);
  }
  float den = exv;
#pragma unroll
  for (int m = 1; m < 64; m <<= 1) den += __shfl_xor(den, m, 64);
  const float winv = 1.f / (den + 1e-16f);
  const short* H2s = (const short*)H2;
  float a0 = 0.f, a1 = 0.f;
  // 2-deep pipelined gather; uniform shfl index -> readlane broadcast
  unsigned int hv = 0;
  float wcur = 0.f;
  {
    int s0 = __shfl(srcv, 0, 64);
    wcur = __shfl(exv, 0, 64);
    hv = *(const unsigned int*)(H2s + (size_t)s0 * 128 + lane * 2);
  }
  for (int k = 1; k <= cn; k++) {
    unsigned int hn = 0;
    float wn = 0.f;
    if (k < cn) {
      int sk = __shfl(srcv, k, 64);
      wn = __shfl(exv, k, 64);
      hn = *(const unsigned int*)(H2s + (size_t)sk * 128 + lane * 2);
    }
    a0 += wcur * sb2f((short)(hv & 0xffff));
    a1 += wcur * sb2f((short)(hv >> 16));
    hv = hn;
    wcur = wn;
  }
  const int c0 = lane * 2;
  float v0 = a0 * winv + b2[c0];
  float v1 = a1 * winv + b2[c0 + 1];
  v0 = v0 > 0.f ? v0 : 0.f;
  v1 = v1 > 0.f ? v1 : 0.f;
  atomicMax((int*)&g[b * 128 + c0], __float_as_int(v0));      // v >= 0
  atomicMax((int*)&g[b * 128 + c0 + 1], __float_as_int(v1));
}

// ---------- final FC + ReLU -> f32 out ----------
__global__ __launch_bounds__(128) void k_fc(const float* __restrict__ g,
                                            const float* __restrict__ fw,
                                            const float* __restrict__ fb,
                                            float* __restrict__ out) {
  const int n = blockIdx.x, t = threadIdx.x;
  __shared__ float grow[128];
  grow[t] = g[n * 128 + t];
  __syncthreads();
  float acc = fb[t];
  for (int k = 0; k < 128; k++) acc += grow[k] * fw[k * 128 + t];
  out[n * 128 + t] = acc > 0.f ? acc : 0.f;
}

extern "C" void kernel_launch(void* const* d_in, const int* in_sizes, int n_in,
                              void* d_out, int out_size, void* d_ws, size_t ws_size,
                              hipStream_t stream) {
  const float* x     = (const float*)d_in[0];
  const int*   ei    = (const int*)d_in[1];
  const int*   batch = (const int*)d_in[2];
  const float* W1    = (const float*)d_in[3];
  const float* as1w  = (const float*)d_in[4];
  const float* ad1w  = (const float*)d_in[5];
  const float* b1    = (const float*)d_in[6];
  const float* W2    = (const float*)d_in[7];
  const float* as2w  = (const float*)d_in[8];
  const float* ad2w  = (const float*)d_in[9];
  const float* b2    = (const float*)d_in[10];
  const float* fcw   = (const float*)d_in[11];
  const float* fcb   = (const float*)d_in[12];
  float* out = (float*)d_out;

  char* p = (char*)d_ws;
  size_t off = 0;
  auto alloc = [&](size_t bytes) -> void* {
    void* r = p + off;
    off = (off + bytes + 15) & ~(size_t)15;
    return r;
  };
  // ---- zero region (cnt + g) ----
  int*   cnt = (int*)  alloc(50000 * 4);
  float* g   = (float*)alloc(160000 * 4);
  size_t zeroWords = off / 4;
  // ---- rest (~191 MB) ----
  float* as1 = (float*)alloc(500000 * 4);
  float* ad1 = (float*)alloc(500000 * 4);
  float* as2 = (float*)alloc(50000 * 4);
  float* ad2 = (float*)alloc(50000 * 4);
  bf16*  W1t = (bf16*) alloc((size_t)832 * 96 * 2);
  bf16*  W2t = (bf16*) alloc((size_t)128 * 832 * 2);
  bf16*  Wat = (bf16*) alloc((size_t)32 * 96 * 2);
  bf16*  h1  = (bf16*) alloc((size_t)50000 * 832 * 2);
  bf16*  hl2 = (bf16*) alloc((size_t)50000 * 832 * 2);
  int*   csr = (int*)  alloc((size_t)50000 * CAP * 4);
  // union: xb (9.6 MB, dead after gemm1) aliases h2 (12.8 MB, born in gemm2)
  void*  uni = alloc((size_t)50000 * 128 * 2);
  bf16*  xb  = (bf16*)uni;
  bf16*  h2  = (bf16*)uni;
  int*   flag = (int*) alloc(16);
  (void)ws_size; (void)in_sizes; (void)n_in; (void)out_size;

  int prepN = 50000 * 12 + 832 * 96 + 128 * 832 + 32 * 96;
  k_prep<<<(prepN + 255) / 256, 256, 0, stream>>>(
      x, W1, W2, as1w, ad1w, xb, W1t, W2t, Wat, (float*)d_ws, (int)zeroWords);

  k_gemm1<<<782, 256, 0, stream>>>(xb, W1t, Wat, b1, h1, as1, ad1);
  k_scatter<<<(150000 + 255) / 256, 256, 0, stream>>>(ei, cnt, csr, flag);
  k_agg1<<<25000, 256, 0, stream>>>(h1, as1, ad1, csr, cnt, hl2);
  k_gemm2<<<782, 256, 0, stream>>>(hl2, W2t, as2w, ad2w, h2, as2, ad2);
  k_agg2<<<12500, 256, 0, stream>>>(h2, as2, ad2, csr, cnt, b2, batch, flag, g);
  k_fc<<<1250, 128, 0, stream>>>(g, fcw, fcb, out);
}

// Round 13
// 268.023 us; speedup vs baseline: 1.1624x; 1.0057x over previous
//
#include <hip/hip_runtime.h>
#include <hip/hip_bf16.h>
#include <cstdint>

#define CAP 32
typedef __hip_bfloat16 bf16;
typedef __attribute__((ext_vector_type(8))) short short8;
typedef __attribute__((ext_vector_type(4))) float f32x4;

__device__ __forceinline__ float sb2f(short s) {
  unsigned int u = ((unsigned int)(unsigned short)s) << 16;
  return __uint_as_float(u);
}
__device__ __forceinline__ short f2sb(float f) {
  bf16 h = __float2bfloat16(f);
  return *reinterpret_cast<short*>(&h);
}

// Head-padded column layout for H1/HL2: col' = 80*h + j, j in [0,78), h in [0,10).
// Cols with j in {78,79} and col' in [800,832) are zero pads. This makes every
// 8-col thread slice in k_agg1 belong to exactly ONE head (1 weight read/row).

__device__ __forceinline__ void edge_sd(const int* __restrict__ ei, int e, int f,
                                        int& src, int& dst) {
  if (e < 100000) {
    if (f) { src = ei[2 * e]; dst = ei[200000 + 2 * e]; }
    else   { src = ei[e];     dst = ei[100000 + e]; }
  } else { src = dst = e - 100000; }
  src = min(max(src, 0), 49999);
  dst = min(max(dst, 0), 49999);
}

// ---------- prep: zero cnt/g + bf16 padded/transposed copies + Wa ----------
// xb path vectorized: one short8 store per thread (8 cols).
__global__ void k_prep(const float* __restrict__ x, const float* __restrict__ W1,
                       const float* __restrict__ W2, const float* __restrict__ aw1,
                       const float* __restrict__ dw1, bf16* __restrict__ xb,
                       bf16* __restrict__ W1t, bf16* __restrict__ W2t,
                       bf16* __restrict__ Wat, float* __restrict__ zp, int zeroWords) {
  int i = blockIdx.x * 256 + threadIdx.x;
  if (i < zeroWords) zp[i] = 0.f;
  const int n_xbv = 50000 * 12;   // short8 groups of xb
  const int n_w1 = 832 * 96;
  const int n_w2 = 128 * 832;
  const int n_wa = 32 * 96;
  if (i < n_xbv) {
    int r = i / 12, kg = i - r * 12;
    const float* xr = x + (size_t)r * 78;
    const int k0 = kg * 8;
    short8 ov;
#pragma unroll
    for (int c = 0; c < 8; c++) {
      int k = k0 + c;
      ov[c] = f2sb(k < 78 ? xr[k] : 0.f);
    }
    *(short8*)((short*)xb + (size_t)r * 96 + k0) = ov;
  } else if (i < n_xbv + n_w1) {
    // W1t row n' = head-padded output column: n' = 80h + j -> source col 78h + j
    int jdx = i - n_xbv;
    int np = jdx / 96, k = jdx - np * 96;
    int h = np / 80, j = np - h * 80;
    float v = 0.f;
    if (k < 78 && np < 800 && j < 78) v = W1[k * 780 + (h * 78 + j)];
    W1t[jdx] = __float2bfloat16(v);
  } else if (i < n_xbv + n_w1 + n_w2) {
    // W2t[c][k'] with head-padded K: k' = 80h + j -> source row 78h + j
    int jdx = i - n_xbv - n_w1;
    int c = jdx / 832, kp = jdx - c * 832;
    int h = kp / 80, j = kp - h * 80;
    float v = 0.f;
    if (kp < 800 && j < 78) v = W2[(h * 78 + j) * 128 + c];
    W2t[jdx] = __float2bfloat16(v);
  } else if (i < n_xbv + n_w1 + n_w2 + n_wa) {
    int jdx = i - n_xbv - n_w1 - n_w2;
    int c = jdx / 96, k = jdx - c * 96;
    float s = 0.f;
    if (k < 78 && c < 20) {
      const float* w = (c < 10) ? aw1 : dw1;
      int h = (c < 10) ? c : c - 10;
      const float* wrow = W1 + k * 780 + h * 78;
      const float* arow = w + h * 78;
      for (int q = 0; q < 78; q++) s += wrow[q] * arow[q];
    }
    Wat[c * 96 + k] = __float2bfloat16(s);
  }
}

// ---------- GEMM1 (MFMA bf16): h1[50000,832] = xb @ W1t^T + b1 (bias folded in) ----------
// LDS lifetime-managed: A-fragments cached in registers after staging (Als dead),
// alpha1 computed up front (Wls dead), then the chunk loop reuses the same LDS
// region for Bls (shorts) and Cls (floats). 54 KB -> 23.3 KB => ~7 blocks/CU.
__global__ __launch_bounds__(256) void k_gemm1(const bf16* __restrict__ xb,
                                               const bf16* __restrict__ W1t,
                                               const bf16* __restrict__ Wat,
                                               const float* __restrict__ b1,
                                               bf16* __restrict__ H1,
                                               float* __restrict__ as1,
                                               float* __restrict__ ad1) {
  // phase 1: [0,13312) = Als (64x104 shorts), [13312,19968) = Wls (32x104 shorts)
  // phase 2: [0,17408) = Bls (64x104 shorts) / Cls (64x68 floats), barrier-separated
  __shared__ __align__(16) char smem[19968];
  __shared__ float b1s[832];
  short* Als = (short*)smem;
  short* Wls = (short*)(smem + 13312);
  short* Bls = (short*)smem;
  float* Cls = (float*)smem;
  const int t = threadIdx.x;
  const int w = t >> 6, l = t & 63, l15 = l & 15, q = l >> 4;
  const int rowBase = blockIdx.x * 64;
  // stage A once (64x96), Wa once (32x96), b1 once (head-padded order)
  for (int s = t; s < 768; s += 256) {
    int row = s / 12, kg = s - row * 12;
    short8 v = {};
    int gr = rowBase + row;
    if (gr < 50000) v = *(const short8*)((const short*)xb + (size_t)gr * 96 + kg * 8);
    *(short8*)&Als[row * 104 + kg * 8] = v;
  }
  for (int s = t; s < 384; s += 256) {
    int row = s / 12, kg = s - row * 12;
    *(short8*)&Wls[row * 104 + kg * 8] =
        *(const short8*)((const short*)Wat + (size_t)row * 96 + kg * 8);
  }
  for (int s = t; s < 832; s += 256) {
    int h = s / 80, j = s - h * 80;
    b1s[s] = (s < 800 && j < 78) ? b1[h * 78 + j] : 0.f;
  }
  __syncthreads();
  // cache A fragments in registers (same 3 LDS slots every chunk)
  short8 afrag[3];
#pragma unroll
  for (int ks = 0; ks < 3; ks++)
    afrag[ks] = *(const short8*)&Als[(w * 16 + l15) * 104 + ks * 32 + q * 8];
  // fused alpha1 up front: [64x96] @ Wa^T (afrag + Wls; no atomics)
  {
    f32x4 acc2[2] = {};
#pragma unroll
    for (int ks = 0; ks < 3; ks++) {
#pragma unroll
      for (int nt = 0; nt < 2; nt++) {
        short8 b = *(const short8*)&Wls[(nt * 16 + l15) * 104 + ks * 32 + q * 8];
        acc2[nt] = __builtin_amdgcn_mfma_f32_16x16x32_bf16(afrag[ks], b, acc2[nt], 0, 0, 0);
      }
    }
    const int gr0 = rowBase + w * 16 + q * 4;
#pragma unroll
    for (int nt = 0; nt < 2; nt++) {
      int c = nt * 16 + l15;
#pragma unroll
      for (int r = 0; r < 4; r++) {
        int gr = gr0 + r;
        if (gr < 50000) {
          if (c < 10)       as1[gr * 10 + c] = acc2[nt][r];
          else if (c < 20)  ad1[gr * 10 + (c - 10)] = acc2[nt][r];
        }
      }
    }
  }
  // prefetch B chunk 0 into registers (3 short8/thread)
  short8 breg[3];
  int bn[3], bk[3];
#pragma unroll
  for (int i = 0; i < 3; i++) {
    int s = t + i * 256;
    bn[i] = s / 12; bk[i] = s - bn[i] * 12;
    breg[i] = *(const short8*)((const short*)W1t + (size_t)bn[i] * 96 + bk[i] * 8);
  }
  for (int cc = 0; cc < 13; cc++) {
    __syncthreads();  // prev Cls consumed (and cc==0: afrag/Wls reads done)
#pragma unroll
    for (int i = 0; i < 3; i++) *(short8*)&Bls[bn[i] * 104 + bk[i] * 8] = breg[i];
    if (cc < 12) {
#pragma unroll
      for (int i = 0; i < 3; i++)
        breg[i] = *(const short8*)((const short*)W1t +
                                   (size_t)((cc + 1) * 64 + bn[i]) * 96 + bk[i] * 8);
    }
    __syncthreads();
    f32x4 acc[4] = {};
#pragma unroll
    for (int ks = 0; ks < 3; ks++) {
#pragma unroll
      for (int nt = 0; nt < 4; nt++) {
        short8 b = *(const short8*)&Bls[(nt * 16 + l15) * 104 + ks * 32 + q * 8];
        acc[nt] = __builtin_amdgcn_mfma_f32_16x16x32_bf16(afrag[ks], b, acc[nt], 0, 0, 0);
      }
    }
    // C transpose via LDS (Cls aliases Bls; all Bls reads done) -> 16-B stores
    __syncthreads();
#pragma unroll
    for (int nt = 0; nt < 4; nt++)
#pragma unroll
      for (int r = 0; r < 4; r++)
        Cls[(w * 16 + q * 4 + r) * 68 + nt * 16 + l15] = acc[nt][r];
    __syncthreads();
    {
      int r = t >> 2, c0 = (t & 3) * 16;
      int gr = rowBase + r;
      if (gr < 50000) {
        short8 o0, o1;
#pragma unroll
        for (int c = 0; c < 8; c++) o0[c] = f2sb(Cls[r * 68 + c0 + c] + b1s[cc * 64 + c0 + c]);
#pragma unroll
        for (int c = 0; c < 8; c++) o1[c] = f2sb(Cls[r * 68 + c0 + 8 + c] + b1s[cc * 64 + c0 + 8 + c]);
        short* dst = (short*)H1 + (size_t)gr * 832 + cc * 64 + c0;
        *(short8*)dst = o0;
        *(short8*)(dst + 8) = o1;
      }
    }
  }
}

// ---------- CSR bucket scatter (src only); per-block int64 detect; publishes flag ----------
__global__ void k_scatter(const int* __restrict__ ei, int* __restrict__ cnt,
                          int* __restrict__ csr, int* __restrict__ flag) {
  __shared__ int sf;
  const int t = threadIdx.x;
  if (t == 0) sf = 0;
  __syncthreads();
  int v = 0;
  for (int i = 1 + 2 * t; i < 2000; i += 512) v |= ei[i];
  if (v) atomicOr(&sf, 1);
  __syncthreads();
  const int f = (sf == 0) ? 1 : 0;  // 1 => int64 layout
  if (blockIdx.x == 0 && t == 0) flag[0] = f;  // for k_agg2 (stream-ordered)
  int e = blockIdx.x * 256 + t;
  if (e >= 150000) return;
  int src, dst;
  edge_sd(ei, e, f, src, dst);
  int pos = atomicAdd(&cnt[dst], 1);
  if (pos < CAP) csr[dst * CAP + pos] = src;
}

// ---------- aggregate layer1: head-padded layout; 1 weight read per row ----------
// 2 nodes per 256-thread block. Gather loop is 2-deep software-pipelined
// (named rotating registers; addresses depend only on ssrc, so two loads
// stay in flight per thread instead of one).
__global__ __launch_bounds__(256) void k_agg1(const bf16* __restrict__ H1,
                                              const float* __restrict__ as1,
                                              const float* __restrict__ ad1,
                                              const int* __restrict__ csr,
                                              const int* __restrict__ cnt,
                                              bf16* __restrict__ HL2) {
  __shared__ float sexw[2][CAP * 10];
  __shared__ float sden[2][16];
  __shared__ int ssrc[2][CAP];
  __shared__ int scnt[2];
  const int t = threadIdx.x;
  const int sub = t >> 7, tt = t & 127;
  const int n = blockIdx.x * 2 + sub;
  if (t < 2) scnt[t] = min(cnt[blockIdx.x * 2 + t], CAP);
  if (t >= 32 && t < 64) { int z = t - 32; sden[z >> 4][z & 15] = 0.f; }
  __syncthreads();
  const int cn = scnt[sub];
  if (tt < cn) ssrc[sub][tt] = csr[n * CAP + tt];
  __syncthreads();
  for (int wv = tt; wv < cn * 10; wv += 128) {
    int k = wv / 10, h = wv - k * 10;
    int src = ssrc[sub][k];
    float e = as1[src * 10 + h] + ad1[n * 10 + h];
    e = e >= 0.f ? e : 0.2f * e;
    float ex = __expf(e);
    sexw[sub][wv] = ex;  // unnormalized; denominator applied in epilogue
    atomicAdd(&sden[sub][h], ex);
  }
  __syncthreads();
  if (tt < 100) {
    const int head = tt / 10;
    const int j0 = tt * 8;
    float acc[8] = {};
    const float* sw = sexw[sub] + head;
    const short* H1s = (const short*)H1;
    // 2-deep pipelined gather (named regs, no runtime-indexed arrays)
    short8 hv0 = {}, hv1 = {};
    float w0 = 0.f, w1 = 0.f;
    if (cn > 0) { hv0 = *(const short8*)(H1s + (size_t)ssrc[sub][0] * 832 + j0); w0 = sw[0]; }
    if (cn > 1) { hv1 = *(const short8*)(H1s + (size_t)ssrc[sub][1] * 832 + j0); w1 = sw[10]; }
    for (int k = 0; k < cn; k++) {
      short8 cur = hv0;
      float wc = w0;
      hv0 = hv1; w0 = w1;
      if (k + 2 < cn) {
        hv1 = *(const short8*)(H1s + (size_t)ssrc[sub][k + 2] * 832 + j0);
        w1 = sw[(k + 2) * 10];
      }
#pragma unroll
      for (int c = 0; c < 8; c++) acc[c] += wc * sb2f(cur[c]);
    }
    const float r0 = 1.f / (sden[sub][head] + 1e-16f);
    short8 ov;
#pragma unroll
    for (int c = 0; c < 8; c++) {
      float v = acc[c] * r0;
      v = v > 0.f ? v : __expf(v) - 1.f;  // within-head pad cols: elu(0)=0
      ov[c] = f2sb(v);
    }
    *(short8*)((short*)HL2 + (size_t)n * 832 + j0) = ov;
  } else if (tt < 104) {
    short8 z = {};
    *(short8*)((short*)HL2 + (size_t)n * 832 + tt * 8) = z;  // cols 800..831 = 0
  }
}

// ---------- GEMM2 (MFMA bf16, reg-prefetch pipeline): h2 = hl2 @ W2t^T, fused alpha2 ----------
// K dimension is in head-padded order (W2t rows permuted/zero-padded to match).
__global__ __launch_bounds__(256) void k_gemm2(const bf16* __restrict__ A,
                                               const bf16* __restrict__ W2t,
                                               const float* __restrict__ AW2,
                                               const float* __restrict__ DW2,
                                               bf16* __restrict__ H2,
                                               float* __restrict__ as2,
                                               float* __restrict__ ad2) {
  __shared__ __align__(16) short Als[64 * 72];
  __shared__ __align__(16) short Bls[128 * 72];
  __shared__ float sAW[128], sDW[128];
  __shared__ float sS[4][64], sD[4][64];
  const int t = threadIdx.x;
  const int w = t >> 6, l = t & 63, l15 = l & 15, q = l >> 4;
  const int rowBase = blockIdx.x * 64;
  if (t < 128) sAW[t] = AW2[t];
  else         sDW[t - 128] = DW2[t - 128];
  const int ar = t >> 2, ak = t & 3;
  short8 areg[2], breg[4];
  {
    int gr0 = rowBase + ar;
#pragma unroll
    for (int i = 0; i < 2; i++) {
      short8 v = {};
      int gr = gr0;
      if (gr < 50000)
        v = *(const short8*)((const short*)A + (size_t)gr * 832 + 0 + (ak * 2 + i) * 8);
      areg[i] = v;
    }
#pragma unroll
    for (int i = 0; i < 4; i++) {
      int s = t + i * 256;
      int col = s >> 3, kg = s & 7;
      breg[i] = *(const short8*)((const short*)W2t + (size_t)col * 832 + 0 + kg * 8);
    }
  }
  f32x4 acc[4][2] = {};
  for (int kb = 0; kb < 832; kb += 64) {
    __syncthreads();
#pragma unroll
    for (int i = 0; i < 2; i++)
      *(short8*)&Als[ar * 72 + (ak * 2 + i) * 8] = areg[i];
#pragma unroll
    for (int i = 0; i < 4; i++) {
      int s = t + i * 256;
      int col = s >> 3, kg = s & 7;
      *(short8*)&Bls[col * 72 + kg * 8] = breg[i];
    }
    if (kb < 768) {
      int kn = kb + 64;
      int gr = rowBase + ar;
#pragma unroll
      for (int i = 0; i < 2; i++) {
        short8 v = {};
        if (gr < 50000)
          v = *(const short8*)((const short*)A + (size_t)gr * 832 + kn + (ak * 2 + i) * 8);
        areg[i] = v;
      }
#pragma unroll
      for (int i = 0; i < 4; i++) {
        int s = t + i * 256;
        int col = s >> 3, kg = s & 7;
        breg[i] = *(const short8*)((const short*)W2t + (size_t)col * 832 + kn + kg * 8);
      }
    }
    __syncthreads();
#pragma unroll
    for (int ks = 0; ks < 2; ks++) {
      short8 a[4];
#pragma unroll
      for (int mt = 0; mt < 4; mt++)
        a[mt] = *(const short8*)&Als[(mt * 16 + l15) * 72 + ks * 32 + q * 8];
#pragma unroll
      for (int ntl = 0; ntl < 2; ntl++) {
        short8 b = *(const short8*)&Bls[((w * 2 + ntl) * 16 + l15) * 72 + ks * 32 + q * 8];
#pragma unroll
        for (int mt = 0; mt < 4; mt++)
          acc[mt][ntl] = __builtin_amdgcn_mfma_f32_16x16x32_bf16(a[mt], b, acc[mt][ntl], 0, 0, 0);
      }
    }
  }
  const int col0 = w * 32 + l15, col1 = col0 + 16;
  const float aw0 = sAW[col0], aw1 = sAW[col1];
  const float dw0 = sDW[col0], dw1 = sDW[col1];
  f32x4 sp[4], dp[4];
#pragma unroll
  for (int mt = 0; mt < 4; mt++) {
    sp[mt] = acc[mt][0] * aw0 + acc[mt][1] * aw1;
    dp[mt] = acc[mt][0] * dw0 + acc[mt][1] * dw1;
  }
#pragma unroll
  for (int m = 1; m < 16; m <<= 1) {
#pragma unroll
    for (int mt = 0; mt < 4; mt++)
#pragma unroll
      for (int r = 0; r < 4; r++) {
        sp[mt][r] += __shfl_xor(sp[mt][r], m, 64);
        dp[mt][r] += __shfl_xor(dp[mt][r], m, 64);
      }
  }
  if (l15 == 0) {
#pragma unroll
    for (int mt = 0; mt < 4; mt++)
#pragma unroll
      for (int r = 0; r < 4; r++) {
        sS[w][mt * 16 + q * 4 + r] = sp[mt][r];
        sD[w][mt * 16 + q * 4 + r] = dp[mt][r];
      }
  }
#pragma unroll
  for (int mt = 0; mt < 4; mt++) {
    int gr0 = rowBase + mt * 16 + q * 4;
#pragma unroll
    for (int ntl = 0; ntl < 2; ntl++) {
      int gc = w * 32 + ntl * 16 + l15;
#pragma unroll
      for (int r = 0; r < 4; r++) {
        int gr = gr0 + r;
        if (gr < 50000) H2[(size_t)gr * 128 + gc] = __float2bfloat16(acc[mt][ntl][r]);
      }
    }
  }
  __syncthreads();
  if (t < 64) {
    int gr = rowBase + t;
    if (gr < 50000) as2[gr] = sS[0][t] + sS[1][t] + sS[2][t] + sS[3][t];
  } else if (t < 128) {
    int r2 = t - 64;
    int gr = rowBase + r2;
    if (gr < 50000) ad2[gr] = sD[0][r2] + sD[1][r2] + sD[2][r2] + sD[3][r2];
  }
}

// ---------- aggregate layer2: ONE WAVE PER NODE (no barriers, no LDS) ----------
// 4 nodes per 256-thread block. Lane k holds edge k's (src, exp); denominator via
// wave shfl reduce; k-loop broadcasts (src,w) via uniform-index shfl (readlane);
// each lane accumulates 2 columns from one ushort2 load (256 B/row coalesced).
__global__ __launch_bounds__(256) void k_agg2(const bf16* __restrict__ H2,
                                              const float* __restrict__ as2,
                                              const float* __restrict__ ad2,
                                              const int* __restrict__ csr,
                                              const int* __restrict__ cnt,
                                              const float* __restrict__ b2,
                                              const int* __restrict__ batch,
                                              const int* __restrict__ flag,
                                              float* __restrict__ g) {
  const int t = threadIdx.x;
  const int wid = t >> 6, lane = t & 63;
  const int n = blockIdx.x * 4 + wid;
  const int f = flag[0];
  int b = f ? batch[2 * n] : batch[n];
  b = min(max(b, 0), 1249);
  const int cn = min(cnt[n], CAP);
  int srcv = 0;
  float exv = 0.f;
  if (lane < cn) {
    srcv = csr[n * CAP + lane];
    float e = as2[srcv] + ad2[n];
    e = e >= 0.f ? e : 0.2f * e;
    exv = __expf(e);
  }
  float den = exv;
#pragma unroll
  for (int m = 1; m < 64; m <<= 1) den += __shfl_xor(den, m, 64);
  const float winv = 1.f / (den + 1e-16f);
  const short* H2s = (const short*)H2;
  float a0 = 0.f, a1 = 0.f;
  // 2-deep pipelined gather; uniform shfl index -> readlane broadcast
  unsigned int hv = 0;
  float wcur = 0.f;
  {
    int s0 = __shfl(srcv, 0, 64);
    wcur = __shfl(exv, 0, 64);
    hv = *(const unsigned int*)(H2s + (size_t)s0 * 128 + lane * 2);
  }
  for (int k = 1; k <= cn; k++) {
    unsigned int hn = 0;
    float wn = 0.f;
    if (k < cn) {
      int sk = __shfl(srcv, k, 64);
      wn = __shfl(exv, k, 64);
      hn = *(const unsigned int*)(H2s + (size_t)sk * 128 + lane * 2);
    }
    a0 += wcur * sb2f((short)(hv & 0xffff));
    a1 += wcur * sb2f((short)(hv >> 16));
    hv = hn;
    wcur = wn;
  }
  const int c0 = lane * 2;
  float v0 = a0 * winv + b2[c0];
  float v1 = a1 * winv + b2[c0 + 1];
  v0 = v0 > 0.f ? v0 : 0.f;
  v1 = v1 > 0.f ? v1 : 0.f;
  atomicMax((int*)&g[b * 128 + c0], __float_as_int(v0));      // v >= 0
  atomicMax((int*)&g[b * 128 + c0 + 1], __float_as_int(v1));
}

// ---------- final FC + ReLU -> f32 out ----------
__global__ __launch_bounds__(128) void k_fc(const float* __restrict__ g,
                                            const float* __restrict__ fw,
                                            const float* __restrict__ fb,
                                            float* __restrict__ out) {
  const int n = blockIdx.x, t = threadIdx.x;
  __shared__ float grow[128];
  grow[t] = g[n * 128 + t];
  __syncthreads();
  float acc = fb[t];
  for (int k = 0; k < 128; k++) acc += grow[k] * fw[k * 128 + t];
  out[n * 128 + t] = acc > 0.f ? acc : 0.f;
}

extern "C" void kernel_launch(void* const* d_in, const int* in_sizes, int n_in,
                              void* d_out, int out_size, void* d_ws, size_t ws_size,
                              hipStream_t stream) {
  const float* x     = (const float*)d_in[0];
  const int*   ei    = (const int*)d_in[1];
  const int*   batch = (const int*)d_in[2];
  const float* W1    = (const float*)d_in[3];
  const float* as1w  = (const float*)d_in[4];
  const float* ad1w  = (const float*)d_in[5];
  const float* b1    = (const float*)d_in[6];
  const float* W2    = (const float*)d_in[7];
  const float* as2w  = (const float*)d_in[8];
  const float* ad2w  = (const float*)d_in[9];
  const float* b2    = (const float*)d_in[10];
  const float* fcw   = (const float*)d_in[11];
  const float* fcb   = (const float*)d_in[12];
  float* out = (float*)d_out;

  char* p = (char*)d_ws;
  size_t off = 0;
  auto alloc = [&](size_t bytes) -> void* {
    void* r = p + off;
    off = (off + bytes + 15) & ~(size_t)15;
    return r;
  };
  // ---- zero region (cnt + g) ----
  int*   cnt = (int*)  alloc(50000 * 4);
  float* g   = (float*)alloc(160000 * 4);
  size_t zeroWords = off / 4;
  // ---- rest (~191 MB) ----
  float* as1 = (float*)alloc(500000 * 4);
  float* ad1 = (float*)alloc(500000 * 4);
  float* as2 = (float*)alloc(50000 * 4);
  float* ad2 = (float*)alloc(50000 * 4);
  bf16*  W1t = (bf16*) alloc((size_t)832 * 96 * 2);
  bf16*  W2t = (bf16*) alloc((size_t)128 * 832 * 2);
  bf16*  Wat = (bf16*) alloc((size_t)32 * 96 * 2);
  bf16*  h1  = (bf16*) alloc((size_t)50000 * 832 * 2);
  bf16*  hl2 = (bf16*) alloc((size_t)50000 * 832 * 2);
  int*   csr = (int*)  alloc((size_t)50000 * CAP * 4);
  // union: xb (9.6 MB, dead after gemm1) aliases h2 (12.8 MB, born in gemm2)
  void*  uni = alloc((size_t)50000 * 128 * 2);
  bf16*  xb  = (bf16*)uni;
  bf16*  h2  = (bf16*)uni;
  int*   flag = (int*) alloc(16);
  (void)ws_size; (void)in_sizes; (void)n_in; (void)out_size;

  int prepN = 50000 * 12 + 832 * 96 + 128 * 832 + 32 * 96;
  k_prep<<<(prepN + 255) / 256, 256, 0, stream>>>(
      x, W1, W2, as1w, ad1w, xb, W1t, W2t, Wat, (float*)d_ws, (int)zeroWords);

  k_gemm1<<<782, 256, 0, stream>>>(xb, W1t, Wat, b1, h1, as1, ad1);
  k_scatter<<<(150000 + 255) / 256, 256, 0, stream>>>(ei, cnt, csr, flag);
  k_agg1<<<25000, 256, 0, stream>>>(h1, as1, ad1, csr, cnt, hl2);
  k_gemm2<<<782, 256, 0, stream>>>(hl2, W2t, as2w, ad2w, h2, as2, ad2);
  k_agg2<<<12500, 256, 0, stream>>>(h2, as2, ad2, csr, cnt, b2, batch, flag, g);
  k_fc<<<1250, 128, 0, stream>>>(g, fcw, fcb, out);
}